// Round 3
// baseline (112.344 us; speedup 1.0000x reference)
//
#include <hip/hip_runtime.h>
#include <cstdint>
#include <cstddef>

// ---------------------------------------------------------------------------
// CosineDistance via exact int8 reconstruction:
//   ref's 9 bit-slice GEMMs == qx (int8) @ qw^T (int8), dequant, 1 - cos.
// R2: removed single-address atomicMax serialization.
// R3: GEMM -> 2-phase double-buffered schedule (T3 minimum recipe), BK=128:
//     STAGE(next) issued before compute(cur), ONE __syncthreads per K-step.
//     32 MFMA / 32KB staged per iteration, 8 iterations.
// ---------------------------------------------------------------------------

#define D_COLS 1024
#define M_ROWS 4096   // x rows
#define N_ROWS 8192   // weight rows
#define BK     128    // K-elements (bytes) per tile

using i32x4 = __attribute__((ext_vector_type(4))) int;

__device__ __forceinline__ void gload_lds16(const void* g, void* lds) {
  __builtin_amdgcn_global_load_lds(
      (const __attribute__((address_space(1))) uint32_t*)g,
      (__attribute__((address_space(3))) uint32_t*)lds, 16, 0, 0);
}

// One block per row (x rows 0..4095, w rows 4096..12287):
// invnorm[row] = 1/||row||, rmax[row] = max|row| * invnorm. No atomics.
__global__ __launch_bounds__(256) void rownorm_kernel(
    const float* __restrict__ x, const float* __restrict__ w,
    float* __restrict__ invnorm, float* __restrict__ rmax) {
  const int row = blockIdx.x;
  const float* a = (row < M_ROWS) ? x + (size_t)row * D_COLS
                                  : w + (size_t)(row - M_ROWS) * D_COLS;
  const float4 v = ((const float4*)a)[threadIdx.x];
  float ss = v.x * v.x + v.y * v.y + v.z * v.z + v.w * v.w;
  float mx = fmaxf(fmaxf(fabsf(v.x), fabsf(v.y)), fmaxf(fabsf(v.z), fabsf(v.w)));
#pragma unroll
  for (int off = 32; off; off >>= 1) {
    ss += __shfl_down(ss, off, 64);
    mx = fmaxf(mx, __shfl_down(mx, off, 64));
  }
  __shared__ float s_ss[4], s_mx[4];
  const int wave = threadIdx.x >> 6, lane = threadIdx.x & 63;
  if (lane == 0) { s_ss[wave] = ss; s_mx[wave] = mx; }
  __syncthreads();
  if (threadIdx.x == 0) {
    float tss = (s_ss[0] + s_ss[1]) + (s_ss[2] + s_ss[3]);
    float tmx = fmaxf(fmaxf(s_mx[0], s_mx[1]), fmaxf(s_mx[2], s_mx[3]));
    float inv = 1.0f / fmaxf(sqrtf(tss), 1e-12f);
    invnorm[row] = inv;
    rmax[row] = tmx * inv;
  }
}

// Single block: scales[0] = max(rmax[0:4096]), scales[1] = max(rmax[4096:12288])
__global__ __launch_bounds__(1024) void scale_reduce_kernel(
    const float* __restrict__ rmax, float* __restrict__ scales) {
  const int t = threadIdx.x;
  float mx = 0.f, mw = 0.f;
  for (int i = t; i < M_ROWS; i += 1024) mx = fmaxf(mx, rmax[i]);
  for (int i = t; i < N_ROWS; i += 1024) mw = fmaxf(mw, rmax[M_ROWS + i]);
#pragma unroll
  for (int off = 32; off; off >>= 1) {
    mx = fmaxf(mx, __shfl_down(mx, off, 64));
    mw = fmaxf(mw, __shfl_down(mw, off, 64));
  }
  __shared__ float smx[16], smw[16];
  const int wave = t >> 6, lane = t & 63;
  if (lane == 0) { smx[wave] = mx; smw[wave] = mw; }
  __syncthreads();
  if (t == 0) {
    float a = 0.f, b = 0.f;
#pragma unroll
    for (int i = 0; i < 16; ++i) { a = fmaxf(a, smx[i]); b = fmaxf(b, smw[i]); }
    scales[0] = a;
    scales[1] = b;
  }
}

// Quantize: q = rint(a * invnorm_row * 127/scale) -> int8, packed 4/thread.
__global__ __launch_bounds__(256) void quant_kernel(
    const float* __restrict__ a, const float* __restrict__ invnorm,
    const float* __restrict__ scale, unsigned int* __restrict__ qout) {
  const int idx = blockIdx.x * 256 + threadIdx.x;     // one float4 per thread
  const float s = 127.0f / scale[0];
  const float4 v = ((const float4*)a)[idx];
  const int row = idx >> 8;                           // 256 float4 per row
  const float f = invnorm[row] * s;
  int q0 = (int)rintf(v.x * f);
  int q1 = (int)rintf(v.y * f);
  int q2 = (int)rintf(v.z * f);
  int q3 = (int)rintf(v.w * f);
  qout[idx] = (unsigned)(q0 & 0xff) | ((unsigned)(q1 & 0xff) << 8) |
              ((unsigned)(q2 & 0xff) << 16) | ((unsigned)(q3 & 0xff) << 24);
}

// int8 GEMM: out[m,n] = 1 - (qx[m,:] . qw[n,:]) * cs
// 128x128 tile, 4 waves (2x2 of 64x64), BK=128, mfma_i32_16x16x64_i8.
// 2-phase double-buffered: STAGE(next) issued before compute(cur);
// one __syncthreads (implicit vmcnt(0)+lgkmcnt(0) drain) per K-step.
// LDS layout per tile: [kchunk 0..7][row 0..127][16B] -- linear dest for
// global_load_lds, conflict-free ds_read_b128 fragments.
__global__ __launch_bounds__(256) void gemm_i8_kernel(
    const char* __restrict__ qx, const char* __restrict__ qw,
    const float* __restrict__ sx, const float* __restrict__ sw,
    float* __restrict__ out) {
  __shared__ char As[2][16384];
  __shared__ char Bs[2][16384];
  const int t = threadIdx.x;
  const int wave = t >> 6, lane = t & 63;
  const int wr = wave >> 1, wc = wave & 1;
  const int rowBase = blockIdx.y * 128;
  const int colBase = blockIdx.x * 128;

  i32x4 acc[4][4] = {};
  const int ko = lane >> 4, rl = lane & 15;

  // ---- stage K-tile `ks` into buffer b: 4 A-chunks + 4 B-chunks per thread
#define STAGE(b, ks)                                                         \
  {                                                                          \
    const int k0_ = (ks) * BK;                                               \
    _Pragma("unroll")                                                        \
    for (int is = 0; is < 4; ++is) {                                         \
      const int cibase = is * 256 + wave * 64;   /* wave-uniform */          \
      const int ck = cibase >> 7;                /* kchunk 0..7, uniform */  \
      const int crb = cibase & 127;              /* row base, uniform */     \
      const int cr = crb + lane;                 /* per-lane row */          \
      gload_lds16(qx + (size_t)(rowBase + cr) * D_COLS + k0_ + ck * 16,      \
                  As[b] + (ck * 128 + crb) * 16);                            \
      gload_lds16(qw + (size_t)(colBase + cr) * D_COLS + k0_ + ck * 16,      \
                  Bs[b] + (ck * 128 + crb) * 16);                            \
    }                                                                        \
  }

  STAGE(0, 0);
  __syncthreads();  // vmcnt(0) drain: tile 0 ready

  int cur = 0;
#pragma unroll 1
  for (int ks = 0; ks < 8; ++ks) {
    if (ks + 1 < 8) {
      if (cur == 0) STAGE(1, ks + 1) else STAGE(0, ks + 1);
    }
    // compute from buf[cur]
    i32x4 af[2][4], bf[2][4];
#pragma unroll
    for (int kh = 0; kh < 2; ++kh) {
#pragma unroll
      for (int m = 0; m < 4; ++m)
        af[kh][m] = *(const i32x4*)(As[cur] +
            ((kh * 4 + ko) * 128 + wr * 64 + m * 16 + rl) * 16);
#pragma unroll
      for (int n = 0; n < 4; ++n)
        bf[kh][n] = *(const i32x4*)(Bs[cur] +
            ((kh * 4 + ko) * 128 + wc * 64 + n * 16 + rl) * 16);
    }
#pragma unroll
    for (int kh = 0; kh < 2; ++kh)
#pragma unroll
      for (int m = 0; m < 4; ++m)
#pragma unroll
        for (int n = 0; n < 4; ++n)
          acc[m][n] = __builtin_amdgcn_mfma_i32_16x16x64_i8(
              af[kh][m], bf[kh][n], acc[m][n], 0, 0, 0);
    __syncthreads();  // drains vmcnt(0): next tile staged; all reads of cur done
    cur ^= 1;
  }
#undef STAGE

  const float cs = sx[0] * sw[0] * (1.0f / 16129.0f);  // (sx/127)*(sw/127)
#pragma unroll
  for (int m = 0; m < 4; ++m) {
    const int row = rowBase + wr * 64 + m * 16 + (lane >> 4) * 4;
#pragma unroll
    for (int n = 0; n < 4; ++n) {
      const int col = colBase + wc * 64 + n * 16 + (lane & 15);
#pragma unroll
      for (int j = 0; j < 4; ++j)
        out[(size_t)(row + j) * N_ROWS + col] = 1.0f - (float)acc[m][n][j] * cs;
    }
  }
}

extern "C" void kernel_launch(void* const* d_in, const int* in_sizes, int n_in,
                              void* d_out, int out_size, void* d_ws, size_t ws_size,
                              hipStream_t stream) {
  const float* x = (const float*)d_in[0];   // [4096, 1024]
  const float* w = (const float*)d_in[1];   // [8192, 1024]
  float* out = (float*)d_out;               // [4096, 8192]

  char* ws = (char*)d_ws;
  char* qx = ws;                                        // 4 MB int8
  char* qw = ws + (size_t)M_ROWS * D_COLS;              // 8 MB int8
  float* invnorm = (float*)(ws + (size_t)(M_ROWS + N_ROWS) * D_COLS);  // [12288]
  float* rmax = invnorm + (M_ROWS + N_ROWS);            // [12288]
  float* scales = rmax + (M_ROWS + N_ROWS);             // [0]=sx, [1]=sw

  rownorm_kernel<<<M_ROWS + N_ROWS, 256, 0, stream>>>(x, w, invnorm, rmax);
  scale_reduce_kernel<<<1, 1024, 0, stream>>>(rmax, scales);

  quant_kernel<<<M_ROWS * (D_COLS / 4) / 256, 256, 0, stream>>>(
      x, invnorm, &scales[0], (unsigned int*)qx);
  quant_kernel<<<N_ROWS * (D_COLS / 4) / 256, 256, 0, stream>>>(
      w, invnorm + M_ROWS, &scales[1], (unsigned int*)qw);

  dim3 grid(N_ROWS / 128, M_ROWS / 128);  // (64, 32)
  gemm_i8_kernel<<<grid, 256, 0, stream>>>(qx, qw, &scales[0], &scales[1], out);
}

// Round 4
// 97.863 us; speedup vs baseline: 1.1480x; 1.1480x over previous
//
#include <hip/hip_runtime.h>
#include <cstdint>
#include <cstddef>

// ---------------------------------------------------------------------------
// CosineDistance via exact int8 reconstruction:
//   ref's 9 bit-slice GEMMs == qx (int8) @ qw^T (int8), dequant, 1 - cos.
// R2: removed single-address atomicMax serialization.
// R3: 2-phase dbuf 128x128 -- FAILED to break latency (90us, MfmaUtil 15%).
// R4: 256x256 deep-pipelined schedule (T3+T4+T5): 8 waves, BK=128B,
//     128KiB LDS dbuf, prefetch distance = 1 full K-tile (vmcnt wait is
//     ~free), raw s_barrier phases (no counter drain), setprio on MFMA.
// ---------------------------------------------------------------------------

#define D_COLS 1024
#define M_ROWS 4096   // x rows
#define N_ROWS 8192   // weight rows

using i32x4 = __attribute__((ext_vector_type(4))) int;

__device__ __forceinline__ void gload_lds16(const void* g, void* lds) {
  __builtin_amdgcn_global_load_lds(
      (const __attribute__((address_space(1))) uint32_t*)g,
      (__attribute__((address_space(3))) uint32_t*)lds, 16, 0, 0);
}

// One block per row (x rows 0..4095, w rows 4096..12287):
// invnorm[row] = 1/||row||, rmax[row] = max|row| * invnorm. No atomics.
__global__ __launch_bounds__(256) void rownorm_kernel(
    const float* __restrict__ x, const float* __restrict__ w,
    float* __restrict__ invnorm, float* __restrict__ rmax) {
  const int row = blockIdx.x;
  const float* a = (row < M_ROWS) ? x + (size_t)row * D_COLS
                                  : w + (size_t)(row - M_ROWS) * D_COLS;
  const float4 v = ((const float4*)a)[threadIdx.x];
  float ss = v.x * v.x + v.y * v.y + v.z * v.z + v.w * v.w;
  float mx = fmaxf(fmaxf(fabsf(v.x), fabsf(v.y)), fmaxf(fabsf(v.z), fabsf(v.w)));
#pragma unroll
  for (int off = 32; off; off >>= 1) {
    ss += __shfl_down(ss, off, 64);
    mx = fmaxf(mx, __shfl_down(mx, off, 64));
  }
  __shared__ float s_ss[4], s_mx[4];
  const int wave = threadIdx.x >> 6, lane = threadIdx.x & 63;
  if (lane == 0) { s_ss[wave] = ss; s_mx[wave] = mx; }
  __syncthreads();
  if (threadIdx.x == 0) {
    float tss = (s_ss[0] + s_ss[1]) + (s_ss[2] + s_ss[3]);
    float tmx = fmaxf(fmaxf(s_mx[0], s_mx[1]), fmaxf(s_mx[2], s_mx[3]));
    float inv = 1.0f / fmaxf(sqrtf(tss), 1e-12f);
    invnorm[row] = inv;
    rmax[row] = tmx * inv;
  }
}

// Single block: scales[0] = max(rmax[0:4096]), scales[1] = max(rmax[4096:12288])
__global__ __launch_bounds__(1024) void scale_reduce_kernel(
    const float* __restrict__ rmax, float* __restrict__ scales) {
  const int t = threadIdx.x;
  float mx = 0.f, mw = 0.f;
  for (int i = t; i < M_ROWS; i += 1024) mx = fmaxf(mx, rmax[i]);
  for (int i = t; i < N_ROWS; i += 1024) mw = fmaxf(mw, rmax[M_ROWS + i]);
#pragma unroll
  for (int off = 32; off; off >>= 1) {
    mx = fmaxf(mx, __shfl_down(mx, off, 64));
    mw = fmaxf(mw, __shfl_down(mw, off, 64));
  }
  __shared__ float smx[16], smw[16];
  const int wave = t >> 6, lane = t & 63;
  if (lane == 0) { smx[wave] = mx; smw[wave] = mw; }
  __syncthreads();
  if (t == 0) {
    float a = 0.f, b = 0.f;
#pragma unroll
    for (int i = 0; i < 16; ++i) { a = fmaxf(a, smx[i]); b = fmaxf(b, smw[i]); }
    scales[0] = a;
    scales[1] = b;
  }
}

// Quantize: q = rint(a * invnorm_row * 127/scale) -> int8, packed 4/thread.
__global__ __launch_bounds__(256) void quant_kernel(
    const float* __restrict__ a, const float* __restrict__ invnorm,
    const float* __restrict__ scale, unsigned int* __restrict__ qout) {
  const int idx = blockIdx.x * 256 + threadIdx.x;     // one float4 per thread
  const float s = 127.0f / scale[0];
  const float4 v = ((const float4*)a)[idx];
  const int row = idx >> 8;                           // 256 float4 per row
  const float f = invnorm[row] * s;
  int q0 = (int)rintf(v.x * f);
  int q1 = (int)rintf(v.y * f);
  int q2 = (int)rintf(v.z * f);
  int q3 = (int)rintf(v.w * f);
  qout[idx] = (unsigned)(q0 & 0xff) | ((unsigned)(q1 & 0xff) << 8) |
              ((unsigned)(q2 & 0xff) << 16) | ((unsigned)(q3 & 0xff) << 24);
}

// ---------------------------------------------------------------------------
// int8 GEMM, 256x256 tile, 8 waves (wr=wid>>2 in 0..1, wc=wid&3 in 0..3),
// per-wave output 128x64 (8 m-frags x 4 n-frags), BK=128 bytes, 8 K-tiles.
//
// LDS (128 KiB): buf p at p*65536; A at +0, B at +32768.
//   A: [half h][ck 0..7][row 0..127][16B]  (half = 128 rows of the 256)
//   -> global_load_lds dest linear (ck,rowbase wave-uniform, +lane*16),
//   -> ds_read_b128 fragments conflict-free (consecutive rows = 16B apart).
//
// Sync ledger (race-free by construction):
//   * stages for kt+1 (into buf p^1) are issued ONLY after the kt boundary
//     barrier, which all waves reach only after their kt-1 reads of p^1
//     completed (lgkm drained before their last kt-1 MFMA).
//   * reads of buf p (tile kt) happen ONLY after the kt boundary
//     (per-wave s_waitcnt vmcnt(0) then s_barrier => all stages landed).
//   * intra-tile raw s_barriers carry no data dependence (scheduling only).
// Boundary vmcnt(0) is ~free: the waited loads were issued 4 phases earlier.
// ---------------------------------------------------------------------------
__global__ __launch_bounds__(512, 2) void gemm_i8_kernel(
    const char* __restrict__ qx, const char* __restrict__ qw,
    const float* __restrict__ sx, const float* __restrict__ sw,
    float* __restrict__ out) {
  __shared__ __align__(16) char L[131072];
  const int t = threadIdx.x;
  const int wave = t >> 6, lane = t & 63;
  const int wr = wave >> 2, wc = wave & 3;
  const int rl = lane & 15, ko = lane >> 4;
  const int rowBase = blockIdx.y * 256;
  const int colBase = blockIdx.x * 256;

  i32x4 acc[8][4] = {};

  // staging geometry: inst i covers chunks [i*512 + wave*64 .. +63]
  const int sck = wave >> 1;          // + i*4 -> kchunk (wave-uniform)
  const int scrb = (wave & 1) * 64;   // row base within half (wave-uniform)

#define STAGE_TILE(p, kt)                                                     \
  {                                                                           \
    const size_t kb = (size_t)(kt) * 128;                                     \
    _Pragma("unroll") for (int h = 0; h < 2; ++h)                             \
    _Pragma("unroll") for (int i = 0; i < 2; ++i) {                           \
      const int ck = i * 4 + sck;                                             \
      gload_lds16(                                                            \
          qx + (size_t)(rowBase + h * 128 + scrb + lane) * D_COLS + kb + ck * 16, \
          L + (p) * 65536 + h * 16384 + (ck * 128 + scrb) * 16);              \
      gload_lds16(                                                            \
          qw + (size_t)(colBase + h * 128 + scrb + lane) * D_COLS + kb + ck * 16, \
          L + (p) * 65536 + 32768 + h * 16384 + (ck * 128 + scrb) * 16);      \
    }                                                                         \
  }

  STAGE_TILE(0, 0);  // prologue: tile 0 in flight

#pragma unroll 1
  for (int kt = 0; kt < 8; ++kt) {
    const int p = kt & 1;
    // ---- K-tile boundary: my loads for kt done, then all waves sync ----
    asm volatile("s_waitcnt vmcnt(0) lgkmcnt(0)\n\ts_barrier" ::: "memory");
    __builtin_amdgcn_sched_barrier(0);
    if (kt < 7) STAGE_TILE(p ^ 1, kt + 1);  // full next tile, issued up-front
    __builtin_amdgcn_sched_barrier(0);

    const char* Ab = L + p * 65536 + wr * 16384;
    const char* Bb = L + p * 65536 + 32768 + (wc >> 1) * 16384;
    const int cb = (wc & 1) * 64;

#pragma unroll
    for (int qm = 0; qm < 2; ++qm) {
      i32x4 af[4][2];
#pragma unroll
      for (int m = 0; m < 4; ++m)
#pragma unroll
        for (int ks = 0; ks < 2; ++ks)
          af[m][ks] = *(const i32x4*)(
              Ab + ((ks * 4 + ko) * 128 + (qm * 4 + m) * 16 + rl) * 16);
#pragma unroll
      for (int qn = 0; qn < 2; ++qn) {
        i32x4 bf[2][2];
#pragma unroll
        for (int n = 0; n < 2; ++n)
#pragma unroll
          for (int ks = 0; ks < 2; ++ks)
            bf[n][ks] = *(const i32x4*)(
                Bb + ((ks * 4 + ko) * 128 + cb + (qn * 2 + n) * 16 + rl) * 16);
        __builtin_amdgcn_s_barrier();   // phase align (no drain)
        __builtin_amdgcn_s_setprio(1);
#pragma unroll
        for (int ks = 0; ks < 2; ++ks)
#pragma unroll
          for (int m = 0; m < 4; ++m)
#pragma unroll
            for (int n = 0; n < 2; ++n)
              acc[qm * 4 + m][qn * 2 + n] = __builtin_amdgcn_mfma_i32_16x16x64_i8(
                  af[m][ks], bf[n][ks], acc[qm * 4 + m][qn * 2 + n], 0, 0, 0);
        __builtin_amdgcn_s_setprio(0);
        __builtin_amdgcn_s_barrier();   // phase align (no drain)
      }
    }
  }
#undef STAGE_TILE

  const float cs = sx[0] * sw[0] * (1.0f / 16129.0f);  // (sx/127)*(sw/127)
#pragma unroll
  for (int m = 0; m < 8; ++m) {
    const int row = rowBase + wr * 128 + m * 16 + ko * 4;
#pragma unroll
    for (int n = 0; n < 4; ++n) {
      const int col = colBase + wc * 64 + n * 16 + rl;
#pragma unroll
      for (int j = 0; j < 4; ++j)
        out[(size_t)(row + j) * N_ROWS + col] = 1.0f - (float)acc[m][n][j] * cs;
    }
  }
}

extern "C" void kernel_launch(void* const* d_in, const int* in_sizes, int n_in,
                              void* d_out, int out_size, void* d_ws, size_t ws_size,
                              hipStream_t stream) {
  const float* x = (const float*)d_in[0];   // [4096, 1024]
  const float* w = (const float*)d_in[1];   // [8192, 1024]
  float* out = (float*)d_out;               // [4096, 8192]

  char* ws = (char*)d_ws;
  char* qx = ws;                                        // 4 MB int8
  char* qw = ws + (size_t)M_ROWS * D_COLS;              // 8 MB int8
  float* invnorm = (float*)(ws + (size_t)(M_ROWS + N_ROWS) * D_COLS);  // [12288]
  float* rmax = invnorm + (M_ROWS + N_ROWS);            // [12288]
  float* scales = rmax + (M_ROWS + N_ROWS);             // [0]=sx, [1]=sw

  rownorm_kernel<<<M_ROWS + N_ROWS, 256, 0, stream>>>(x, w, invnorm, rmax);
  scale_reduce_kernel<<<1, 1024, 0, stream>>>(rmax, scales);

  quant_kernel<<<M_ROWS * (D_COLS / 4) / 256, 256, 0, stream>>>(
      x, invnorm, &scales[0], (unsigned int*)qx);
  quant_kernel<<<N_ROWS * (D_COLS / 4) / 256, 256, 0, stream>>>(
      w, invnorm + M_ROWS, &scales[1], (unsigned int*)qw);

  dim3 grid(N_ROWS / 256, M_ROWS / 256);  // (32, 16) = 512 blocks
  gemm_i8_kernel<<<grid, 512, 0, stream>>>(qx, qw, &scales[0], &scales[1], out);
}

// Round 5
// 90.961 us; speedup vs baseline: 1.2351x; 1.0759x over previous
//
#include <hip/hip_runtime.h>
#include <cstdint>
#include <cstddef>

// ---------------------------------------------------------------------------
// CosineDistance via exact int8 reconstruction:
//   ref's 9 bit-slice GEMMs == qx (int8) @ qw^T (int8), dequant, 1 - cos.
// R2: removed single-address atomicMax serialization.
// R3: 2-phase dbuf 128x128 -- no latency win (90us, MfmaUtil 15%).
// R4: 256x256 deep pipeline -- still 87us/15%: staging was lane->row
//     SCATTERED (16B used per 128B line = 8x L2 over-traffic ~2GB).
// R5: quant kernels emit the GEMM's LDS image layout directly:
//     qimg[panel 256 rows][kt][ck 0..7][rr 0..255][16B]. GEMM staging is
//     now 1KB-contiguous per instruction (100% line util). Schedule kept.
// ---------------------------------------------------------------------------

#define D_COLS 1024
#define M_ROWS 4096   // x rows
#define N_ROWS 8192   // weight rows

using i32x4 = __attribute__((ext_vector_type(4))) int;

__device__ __forceinline__ void gload_lds16(const void* g, void* lds) {
  __builtin_amdgcn_global_load_lds(
      (const __attribute__((address_space(1))) uint32_t*)g,
      (__attribute__((address_space(3))) uint32_t*)lds, 16, 0, 0);
}

// One block per row (x rows 0..4095, w rows 4096..12287):
// invnorm[row] = 1/||row||, rmax[row] = max|row| * invnorm. No atomics.
__global__ __launch_bounds__(256) void rownorm_kernel(
    const float* __restrict__ x, const float* __restrict__ w,
    float* __restrict__ invnorm, float* __restrict__ rmax) {
  const int row = blockIdx.x;
  const float* a = (row < M_ROWS) ? x + (size_t)row * D_COLS
                                  : w + (size_t)(row - M_ROWS) * D_COLS;
  const float4 v = ((const float4*)a)[threadIdx.x];
  float ss = v.x * v.x + v.y * v.y + v.z * v.z + v.w * v.w;
  float mx = fmaxf(fmaxf(fabsf(v.x), fabsf(v.y)), fmaxf(fabsf(v.z), fabsf(v.w)));
#pragma unroll
  for (int off = 32; off; off >>= 1) {
    ss += __shfl_down(ss, off, 64);
    mx = fmaxf(mx, __shfl_down(mx, off, 64));
  }
  __shared__ float s_ss[4], s_mx[4];
  const int wave = threadIdx.x >> 6, lane = threadIdx.x & 63;
  if (lane == 0) { s_ss[wave] = ss; s_mx[wave] = mx; }
  __syncthreads();
  if (threadIdx.x == 0) {
    float tss = (s_ss[0] + s_ss[1]) + (s_ss[2] + s_ss[3]);
    float tmx = fmaxf(fmaxf(s_mx[0], s_mx[1]), fmaxf(s_mx[2], s_mx[3]));
    float inv = 1.0f / fmaxf(sqrtf(tss), 1e-12f);
    invnorm[row] = inv;
    rmax[row] = tmx * inv;
  }
}

// Single block: scales[0] = max(rmax[0:4096]), scales[1] = max(rmax[4096:12288])
__global__ __launch_bounds__(1024) void scale_reduce_kernel(
    const float* __restrict__ rmax, float* __restrict__ scales) {
  const int t = threadIdx.x;
  float mx = 0.f, mw = 0.f;
  for (int i = t; i < M_ROWS; i += 1024) mx = fmaxf(mx, rmax[i]);
  for (int i = t; i < N_ROWS; i += 1024) mw = fmaxf(mw, rmax[M_ROWS + i]);
#pragma unroll
  for (int off = 32; off; off >>= 1) {
    mx = fmaxf(mx, __shfl_down(mx, off, 64));
    mw = fmaxf(mw, __shfl_down(mw, off, 64));
  }
  __shared__ float smx[16], smw[16];
  const int wave = t >> 6, lane = t & 63;
  if (lane == 0) { smx[wave] = mx; smw[wave] = mw; }
  __syncthreads();
  if (t == 0) {
    float a = 0.f, b = 0.f;
#pragma unroll
    for (int i = 0; i < 16; ++i) { a = fmaxf(a, smx[i]); b = fmaxf(b, smw[i]); }
    scales[0] = a;
    scales[1] = b;
  }
}

// Quantize into the blocked GEMM image:
//   img uint4 index idx = ((p*64) + cc)*256 + rr   (cc = kt*8+ck in 0..63)
//   source: row r = p*256+rr, floats [r*1024 + cc*16 .. +15]
// Thread = one 16B output chunk: reads 64B contiguous, writes 16B; writes
// are fully coalesced across threads (consecutive idx).
__global__ __launch_bounds__(256) void quant_blocked_kernel(
    const float* __restrict__ a, const float* __restrict__ invnorm,
    const float* __restrict__ scale, uint4* __restrict__ img) {
  const int idx = blockIdx.x * 256 + threadIdx.x;
  const int rr = idx & 255;
  const int cc = (idx >> 8) & 63;
  const int p = idx >> 14;
  const int r = p * 256 + rr;
  const float f = invnorm[r] * (127.0f / scale[0]);
  const float4* src = (const float4*)(a + (size_t)r * D_COLS + cc * 16);
  unsigned pk[4];
#pragma unroll
  for (int q = 0; q < 4; ++q) {
    const float4 v = src[q];
    const int q0 = (int)rintf(v.x * f), q1 = (int)rintf(v.y * f);
    const int q2 = (int)rintf(v.z * f), q3 = (int)rintf(v.w * f);
    pk[q] = (unsigned)(q0 & 0xff) | ((unsigned)(q1 & 0xff) << 8) |
            ((unsigned)(q2 & 0xff) << 16) | ((unsigned)(q3 & 0xff) << 24);
  }
  img[idx] = make_uint4(pk[0], pk[1], pk[2], pk[3]);
}

// ---------------------------------------------------------------------------
// int8 GEMM, 256x256 tile, 8 waves (wr=wid>>2, wc=wid&3), BK=128B, 8 K-tiles,
// mfma_i32_16x16x64_i8, per-wave output 128x64.
//
// Inputs are pre-blocked: slab for (panel P, kt) = 32KB contiguous at
// (P*8+kt)*32768, layout [ck 0..7][rr 0..255][16B] == the LDS image.
// STAGE: per wave 4+4 instructions, each 1KB fully-contiguous global -> LDS
// linear. Fragment ds_read_b128: addr=(ck*256+rr)*16 -> rr*4 words -> banks
// spread, 2-way max (free). Measured 0 conflicts with this layout (R4).
//
// Sync ledger (unchanged from R4): stages for kt+1 issued only after the kt
// boundary barrier; reads of buf p only after per-wave vmcnt(0)+s_barrier.
// ---------------------------------------------------------------------------
__global__ __launch_bounds__(512, 2) void gemm_i8_kernel(
    const char* __restrict__ qx, const char* __restrict__ qw,
    const float* __restrict__ sx, const float* __restrict__ sw,
    float* __restrict__ out) {
  __shared__ __align__(16) char L[131072];
  const int t = threadIdx.x;
  const int wave = t >> 6, lane = t & 63;
  const int wr = wave >> 2, wc = wave & 3;
  const int rl = lane & 15, ko = lane >> 4;

  i32x4 acc[8][4] = {};

#define STAGE_TILE(pp, kt)                                                    \
  {                                                                           \
    const char* sa = qx + ((size_t)blockIdx.y * 8 + (kt)) * 32768;            \
    const char* sb = qw + ((size_t)blockIdx.x * 8 + (kt)) * 32768;            \
    _Pragma("unroll") for (int i = 0; i < 4; ++i) {                           \
      gload_lds16(sa + wave * 4096 + i * 1024 + lane * 16,                    \
                  L + (pp) * 65536 + wave * 4096 + i * 1024);                 \
      gload_lds16(sb + wave * 4096 + i * 1024 + lane * 16,                    \
                  L + (pp) * 65536 + 32768 + wave * 4096 + i * 1024);         \
    }                                                                         \
  }

  STAGE_TILE(0, 0);  // prologue: tile 0 in flight

#pragma unroll 1
  for (int kt = 0; kt < 8; ++kt) {
    const int p = kt & 1;
    // ---- K-tile boundary: my loads for kt done, then all waves sync ----
    asm volatile("s_waitcnt vmcnt(0) lgkmcnt(0)\n\ts_barrier" ::: "memory");
    __builtin_amdgcn_sched_barrier(0);
    if (kt < 7) STAGE_TILE(p ^ 1, kt + 1);  // full next tile, issued up-front
    __builtin_amdgcn_sched_barrier(0);

    const char* Ab = L + p * 65536;
    const char* Bb = L + p * 65536 + 32768;

#pragma unroll
    for (int qm = 0; qm < 2; ++qm) {
      i32x4 af[4][2];
#pragma unroll
      for (int m = 0; m < 4; ++m)
#pragma unroll
        for (int ks = 0; ks < 2; ++ks)
          af[m][ks] = *(const i32x4*)(Ab +
              ((ks * 4 + ko) * 256 + wr * 128 + (qm * 4 + m) * 16 + rl) * 16);
#pragma unroll
      for (int qn = 0; qn < 2; ++qn) {
        i32x4 bf[2][2];
#pragma unroll
        for (int n = 0; n < 2; ++n)
#pragma unroll
          for (int ks = 0; ks < 2; ++ks)
            bf[n][ks] = *(const i32x4*)(Bb +
                ((ks * 4 + ko) * 256 + wc * 64 + (qn * 2 + n) * 16 + rl) * 16);
        __builtin_amdgcn_s_barrier();   // phase align (no drain)
        __builtin_amdgcn_s_setprio(1);
#pragma unroll
        for (int ks = 0; ks < 2; ++ks)
#pragma unroll
          for (int m = 0; m < 4; ++m)
#pragma unroll
            for (int n = 0; n < 2; ++n)
              acc[qm * 4 + m][qn * 2 + n] = __builtin_amdgcn_mfma_i32_16x16x64_i8(
                  af[m][ks], bf[n][ks], acc[qm * 4 + m][qn * 2 + n], 0, 0, 0);
        __builtin_amdgcn_s_setprio(0);
        __builtin_amdgcn_s_barrier();   // phase align (no drain)
      }
    }
  }
#undef STAGE_TILE

  const float cs = sx[0] * sw[0] * (1.0f / 16129.0f);  // (sx/127)*(sw/127)
  const int rowBase = blockIdx.y * 256;
  const int colBase = blockIdx.x * 256;
#pragma unroll
  for (int m = 0; m < 8; ++m) {
    const int row = rowBase + wr * 128 + m * 16 + ko * 4;
#pragma unroll
    for (int n = 0; n < 4; ++n) {
      const int col = colBase + wc * 64 + n * 16 + rl;
#pragma unroll
      for (int j = 0; j < 4; ++j)
        out[(size_t)(row + j) * N_ROWS + col] = 1.0f - (float)acc[m][n][j] * cs;
    }
  }
}

extern "C" void kernel_launch(void* const* d_in, const int* in_sizes, int n_in,
                              void* d_out, int out_size, void* d_ws, size_t ws_size,
                              hipStream_t stream) {
  const float* x = (const float*)d_in[0];   // [4096, 1024]
  const float* w = (const float*)d_in[1];   // [8192, 1024]
  float* out = (float*)d_out;               // [4096, 8192]

  char* ws = (char*)d_ws;
  char* qx = ws;                                        // 4 MB blocked image
  char* qw = ws + (size_t)M_ROWS * D_COLS;              // 8 MB blocked image
  float* invnorm = (float*)(ws + (size_t)(M_ROWS + N_ROWS) * D_COLS);  // [12288]
  float* rmax = invnorm + (M_ROWS + N_ROWS);            // [12288]
  float* scales = rmax + (M_ROWS + N_ROWS);             // [0]=sx, [1]=sw

  rownorm_kernel<<<M_ROWS + N_ROWS, 256, 0, stream>>>(x, w, invnorm, rmax);
  scale_reduce_kernel<<<1, 1024, 0, stream>>>(rmax, scales);

  quant_blocked_kernel<<<M_ROWS * (D_COLS / 16) / 256, 256, 0, stream>>>(
      x, invnorm, &scales[0], (uint4*)qx);
  quant_blocked_kernel<<<N_ROWS * (D_COLS / 16) / 256, 256, 0, stream>>>(
      w, invnorm + M_ROWS, &scales[1], (uint4*)qw);

  dim3 grid(N_ROWS / 256, M_ROWS / 256);  // (32, 16) = 512 blocks
  gemm_i8_kernel<<<grid, 512, 0, stream>>>(qx, qw, &scales[0], &scales[1], out);
}

// Round 6
// 88.169 us; speedup vs baseline: 1.2742x; 1.0317x over previous
//
#include <hip/hip_runtime.h>
#include <cstdint>
#include <cstddef>

// ---------------------------------------------------------------------------
// CosineDistance via exact int8 reconstruction:
//   ref's 9 bit-slice GEMMs == qx (int8) @ qw^T (int8), dequant, 1 - cos.
// R2: removed single-address atomicMax serialization.
// R3: 2-phase dbuf 128x128 -- no latency win (90us, MfmaUtil 15%).
// R4: 256x256 deep pipeline, vmcnt(0) boundaries -- 87us, staging scattered.
// R5: pre-blocked qx/qw images (contiguous staging) -- gemm ~<70us.
// R6: TRUE counted-vmcnt ring pipeline (T3+T4): 16 half-K-tile phases,
//     4-buffer LDS ring, vmcnt(12) steady state (3 half-tiles in flight,
//     never drains to 0 mid-loop), 2 barriers/phase, setprio on MFMA.
// ---------------------------------------------------------------------------

#define D_COLS 1024
#define M_ROWS 4096   // x rows
#define N_ROWS 8192   // weight rows

using i32x4 = __attribute__((ext_vector_type(4))) int;

__device__ __forceinline__ void gload_lds16(const void* g, void* lds) {
  __builtin_amdgcn_global_load_lds(
      (const __attribute__((address_space(1))) uint32_t*)g,
      (__attribute__((address_space(3))) uint32_t*)lds, 16, 0, 0);
}

// One block per row (x rows 0..4095, w rows 4096..12287):
// invnorm[row] = 1/||row||, rmax[row] = max|row| * invnorm. No atomics.
__global__ __launch_bounds__(256) void rownorm_kernel(
    const float* __restrict__ x, const float* __restrict__ w,
    float* __restrict__ invnorm, float* __restrict__ rmax) {
  const int row = blockIdx.x;
  const float* a = (row < M_ROWS) ? x + (size_t)row * D_COLS
                                  : w + (size_t)(row - M_ROWS) * D_COLS;
  const float4 v = ((const float4*)a)[threadIdx.x];
  float ss = v.x * v.x + v.y * v.y + v.z * v.z + v.w * v.w;
  float mx = fmaxf(fmaxf(fabsf(v.x), fabsf(v.y)), fmaxf(fabsf(v.z), fabsf(v.w)));
#pragma unroll
  for (int off = 32; off; off >>= 1) {
    ss += __shfl_down(ss, off, 64);
    mx = fmaxf(mx, __shfl_down(mx, off, 64));
  }
  __shared__ float s_ss[4], s_mx[4];
  const int wave = threadIdx.x >> 6, lane = threadIdx.x & 63;
  if (lane == 0) { s_ss[wave] = ss; s_mx[wave] = mx; }
  __syncthreads();
  if (threadIdx.x == 0) {
    float tss = (s_ss[0] + s_ss[1]) + (s_ss[2] + s_ss[3]);
    float tmx = fmaxf(fmaxf(s_mx[0], s_mx[1]), fmaxf(s_mx[2], s_mx[3]));
    float inv = 1.0f / fmaxf(sqrtf(tss), 1e-12f);
    invnorm[row] = inv;
    rmax[row] = tmx * inv;
  }
}

// Single block: scales[0] = max(rmax[0:4096]), scales[1] = max(rmax[4096:12288])
__global__ __launch_bounds__(1024) void scale_reduce_kernel(
    const float* __restrict__ rmax, float* __restrict__ scales) {
  const int t = threadIdx.x;
  float mx = 0.f, mw = 0.f;
  for (int i = t; i < M_ROWS; i += 1024) mx = fmaxf(mx, rmax[i]);
  for (int i = t; i < N_ROWS; i += 1024) mw = fmaxf(mw, rmax[M_ROWS + i]);
#pragma unroll
  for (int off = 32; off; off >>= 1) {
    mx = fmaxf(mx, __shfl_down(mx, off, 64));
    mw = fmaxf(mw, __shfl_down(mw, off, 64));
  }
  __shared__ float smx[16], smw[16];
  const int wave = t >> 6, lane = t & 63;
  if (lane == 0) { smx[wave] = mx; smw[wave] = mw; }
  __syncthreads();
  if (t == 0) {
    float a = 0.f, b = 0.f;
#pragma unroll
    for (int i = 0; i < 16; ++i) { a = fmaxf(a, smx[i]); b = fmaxf(b, smw[i]); }
    scales[0] = a;
    scales[1] = b;
  }
}

// Quantize into the blocked GEMM image:
//   img uint4 index idx = ((p*64) + cc)*256 + rr   (cc = kt*8+ck in 0..63)
//   source: row r = p*256+rr, floats [r*1024 + cc*16 .. +15]
__global__ __launch_bounds__(256) void quant_blocked_kernel(
    const float* __restrict__ a, const float* __restrict__ invnorm,
    const float* __restrict__ scale, uint4* __restrict__ img) {
  const int idx = blockIdx.x * 256 + threadIdx.x;
  const int rr = idx & 255;
  const int cc = (idx >> 8) & 63;
  const int p = idx >> 14;
  const int r = p * 256 + rr;
  const float f = invnorm[r] * (127.0f / scale[0]);
  const float4* src = (const float4*)(a + (size_t)r * D_COLS + cc * 16);
  unsigned pk[4];
#pragma unroll
  for (int q = 0; q < 4; ++q) {
    const float4 v = src[q];
    const int q0 = (int)rintf(v.x * f), q1 = (int)rintf(v.y * f);
    const int q2 = (int)rintf(v.z * f), q3 = (int)rintf(v.w * f);
    pk[q] = (unsigned)(q0 & 0xff) | ((unsigned)(q1 & 0xff) << 8) |
            ((unsigned)(q2 & 0xff) << 16) | ((unsigned)(q3 & 0xff) << 24);
  }
  img[idx] = make_uint4(pk[0], pk[1], pk[2], pk[3]);
}

// ---------------------------------------------------------------------------
// int8 GEMM, 256x256 tile, 8 waves (wr=wid>>2, wc=wid&3), BK=128B, 8 K-tiles
// = 16 half-K-tile phases, mfma_i32_16x16x64_i8, per-wave output 128x64.
//
// Pre-blocked input slabs: (panel P, kt) = 32KB at (P*8+kt)*32768, layout
// [ck 0..7][rr 0..255][16B]; half-tile ks uses bytes ks*16384 .. +16383.
//
// LDS: 4-buffer ring, buf b = 32KB at b*32768 (A-half 16KB + B-half 16KB).
// Phase h (h=0..15; kt=h>>1, ks=h&1, buf=h&3):
//   1. issue stage for half-tile h+3 into buf (h+3)&3   [4 x gload_lds 1KB]
//   2. s_waitcnt vmcnt(12)  -- drains ONLY h's 4 loads (counted, T4)
//   3. s_barrier            -- all waves' h loads landed
//   4. 12 x ds_read_b128 fragments, 32 MFMA (setprio 1)
//   5. s_barrier            -- all reads of buf h done -> h+4 may overwrite
// Ledger: buf (h+3)&3 == (h-1)&3 is rewritten only after phase h-1's
// trailing barrier (all reads consumed pre-barrier via lgkm waits);
// reads of buf h only after per-wave vmcnt drain + barrier. Tail phases
// 13/14/15 wait vmcnt(8/4/0). Barrier count uniform across waves.
// ---------------------------------------------------------------------------
__global__ __launch_bounds__(512, 2) void gemm_i8_kernel(
    const char* __restrict__ qx, const char* __restrict__ qw,
    const float* __restrict__ sx, const float* __restrict__ sw,
    float* __restrict__ out) {
  __shared__ __align__(16) char L[131072];
  const int t = threadIdx.x;
  const int wave = t >> 6, lane = t & 63;
  const int wr = wave >> 2, wc = wave & 3;
  const int rl = lane & 15, ko = lane >> 4;

  i32x4 acc[8][4] = {};

#define ISSUE_HT(h)                                                           \
  {                                                                           \
    const int kt_ = (h) >> 1, ks_ = (h) & 1, bb_ = (h) & 3;                   \
    const char* sa_ = qx + ((size_t)blockIdx.y * 8 + kt_) * 32768 + ks_ * 16384; \
    const char* sb_ = qw + ((size_t)blockIdx.x * 8 + kt_) * 32768 + ks_ * 16384; \
    _Pragma("unroll") for (int i_ = 0; i_ < 2; ++i_) {                        \
      gload_lds16(sa_ + wave * 2048 + i_ * 1024 + lane * 16,                  \
                  L + bb_ * 32768 + wave * 2048 + i_ * 1024);                 \
      gload_lds16(sb_ + wave * 2048 + i_ * 1024 + lane * 16,                  \
                  L + bb_ * 32768 + 16384 + wave * 2048 + i_ * 1024);         \
    }                                                                         \
  }

#define PHASE(h, VM)                                                          \
  {                                                                           \
    if ((h) + 3 < 16) ISSUE_HT((h) + 3);                                      \
    asm volatile("s_waitcnt vmcnt(" #VM ")" ::: "memory");                    \
    asm volatile("s_barrier" ::: "memory");                                   \
    const char* Ab_ = L + ((h) & 3) * 32768;                                  \
    const char* Bb_ = Ab_ + 16384;                                            \
    i32x4 af_[8], bf_[4];                                                     \
    _Pragma("unroll") for (int m_ = 0; m_ < 8; ++m_)                          \
      af_[m_] = *(const i32x4*)(Ab_ + (ko * 256 + wr * 128 + m_ * 16 + rl) * 16); \
    _Pragma("unroll") for (int n_ = 0; n_ < 4; ++n_)                          \
      bf_[n_] = *(const i32x4*)(Bb_ + (ko * 256 + wc * 64 + n_ * 16 + rl) * 16); \
    __builtin_amdgcn_s_setprio(1);                                            \
    _Pragma("unroll") for (int m_ = 0; m_ < 8; ++m_)                          \
      _Pragma("unroll") for (int n_ = 0; n_ < 4; ++n_)                        \
        acc[m_][n_] = __builtin_amdgcn_mfma_i32_16x16x64_i8(                  \
            af_[m_], bf_[n_], acc[m_][n_], 0, 0, 0);                          \
    __builtin_amdgcn_s_setprio(0);                                            \
    asm volatile("s_barrier" ::: "memory");                                   \
  }

  // prologue: half-tiles 0,1,2 in flight (12 loads)
  ISSUE_HT(0);
  ISSUE_HT(1);
  ISSUE_HT(2);

#pragma unroll 1
  for (int h = 0; h < 13; ++h) PHASE(h, 12);
  PHASE(13, 8);
  PHASE(14, 4);
  PHASE(15, 0);
#undef PHASE
#undef ISSUE_HT

  const float cs = sx[0] * sw[0] * (1.0f / 16129.0f);  // (sx/127)*(sw/127)
  const int rowBase = blockIdx.y * 256;
  const int colBase = blockIdx.x * 256;
#pragma unroll
  for (int m = 0; m < 8; ++m) {
    const int row = rowBase + wr * 128 + m * 16 + ko * 4;
#pragma unroll
    for (int n = 0; n < 4; ++n) {
      const int col = colBase + wc * 64 + n * 16 + rl;
#pragma unroll
      for (int j = 0; j < 4; ++j)
        out[(size_t)(row + j) * N_ROWS + col] = 1.0f - (float)acc[m][n][j] * cs;
    }
  }
}

extern "C" void kernel_launch(void* const* d_in, const int* in_sizes, int n_in,
                              void* d_out, int out_size, void* d_ws, size_t ws_size,
                              hipStream_t stream) {
  const float* x = (const float*)d_in[0];   // [4096, 1024]
  const float* w = (const float*)d_in[1];   // [8192, 1024]
  float* out = (float*)d_out;               // [4096, 8192]

  char* ws = (char*)d_ws;
  char* qx = ws;                                        // 4 MB blocked image
  char* qw = ws + (size_t)M_ROWS * D_COLS;              // 8 MB blocked image
  float* invnorm = (float*)(ws + (size_t)(M_ROWS + N_ROWS) * D_COLS);  // [12288]
  float* rmax = invnorm + (M_ROWS + N_ROWS);            // [12288]
  float* scales = rmax + (M_ROWS + N_ROWS);             // [0]=sx, [1]=sw

  rownorm_kernel<<<M_ROWS + N_ROWS, 256, 0, stream>>>(x, w, invnorm, rmax);
  scale_reduce_kernel<<<1, 1024, 0, stream>>>(rmax, scales);

  quant_blocked_kernel<<<M_ROWS * (D_COLS / 16) / 256, 256, 0, stream>>>(
      x, invnorm, &scales[0], (uint4*)qx);
  quant_blocked_kernel<<<N_ROWS * (D_COLS / 16) / 256, 256, 0, stream>>>(
      w, invnorm + M_ROWS, &scales[1], (uint4*)qw);

  dim3 grid(N_ROWS / 256, M_ROWS / 256);  // (32, 16) = 512 blocks
  gemm_i8_kernel<<<grid, 512, 0, stream>>>(qx, qw, &scales[0], &scales[1], out);
}